// Round 11
// baseline (266.033 us; speedup 1.0000x reference)
//
#include <hip/hip_runtime.h>
#include <hip/hip_fp16.h>

#define S_DIM 512
#define B_DIM 256
#define H_DIM 500
#define M_DIM (S_DIM * B_DIM)     // 131072

typedef _Float16 half8_t __attribute__((ext_vector_type(8)));
typedef float    f32x4  __attribute__((ext_vector_type(4)));

// workspace layout (bytes)
#define WS_W2I 0                       // fp16 image [64 planes][512 slots][8] = 512 KB
#define WS_AT  (512 * 1024)            // fp32 At[h][b] [512][256]   = 512 KB
#define WS_VP  (1024 * 1024)           // fp32 [512]
#define WS_SC  (1024 * 1024 + 4096)    // fp32 [4][131072] partial scores = 2 MB

__device__ __forceinline__ void gld_lds16(const void* g, void* l) {
    __builtin_amdgcn_global_load_lds(
        (const __attribute__((address_space(1))) unsigned int*)g,
        (__attribute__((address_space(3))) unsigned int*)l, 16, 0, 0);
}

// ---- prep: W2 -> fp16 image, plane p = ks*4 + (n>>7); slot = nl*4 + cL,
// cL = ce ^ ((nl>>1)&3)  (R8-measured 0-conflict swizzle), 8 halves/slot.
__global__ void prep_w2_v(const float* __restrict__ W, const float* __restrict__ v,
                          _Float16* __restrict__ W2i, float* __restrict__ vp) {
    int idx = blockIdx.x * blockDim.x + threadIdx.x;   // 0..131071
#pragma unroll
    for (int r = 0; r < 2; ++r) {
        int e = idx + r * 131072;                      // 0..262143
        int n = e >> 9, k = e & 511;
        float val = (n < H_DIM && k < H_DIM) ? W[n * 1000 + 500 + k] : 0.0f;
        int nb = n >> 7, nl = n & 127, ks = k >> 5, ce = (k >> 3) & 3, u = k & 7;
        int cL = ce ^ ((nl >> 1) & 3);
        W2i[(((ks * 4 + nb) * 512) + nl * 4 + cL) * 8 + u] = (_Float16)val;
    }
    if (idx < 512) vp[idx] = (idx < H_DIM) ? v[idx] : 0.0f;
}

// ---- prep: At[h][b] = b_attn[h] + hidden[b,:] . W1[h,:]  (exact fp32, transposed) ----
__global__ void prep_A(const float* __restrict__ hidden, const float* __restrict__ W,
                       const float* __restrict__ b_attn, float* __restrict__ At) {
    int b = blockIdx.x;
    int t = threadIdx.x;               // 0..511 = h
    __shared__ float hs[512];
    hs[t] = (t < H_DIM) ? hidden[b * H_DIM + t] : 0.0f;
    __syncthreads();
    float acc = 0.0f;
    if (t < H_DIM) {
        acc = b_attn[t];
        const float4* wr = (const float4*)(W + t * 1000);
        const float4* hr = (const float4*)hs;
#pragma unroll 5
        for (int i = 0; i < 125; ++i) {
            float4 w4 = wr[i], h4 = hr[i];
            acc += w4.x * h4.x + w4.y * h4.y + w4.z * h4.z + w4.w * h4.w;
        }
    }
    At[t * B_DIM + b] = acc;
}

// ---- main: m97-exact geometry. 256 thr = 4 waves (2M x 2N), tile 128x128, BK=32,
// LDS 33 KB -> 3 blocks/CU (independent barrier groups overlap drains — m114/m97).
// Default 256-reg cap (~150 used) -> NO spill. N-split 4, XCD-chunked n-innermost.
// A: reg-staged fp32->fp16, R8-proven swizzle. B: global_load_lds from image.
__launch_bounds__(256)
__global__ void fused_attn_gemm(const float* __restrict__ enc,
                                const _Float16* __restrict__ W2i,
                                const float* __restrict__ At,
                                const float* __restrict__ vp,
                                float* __restrict__ sct) {
    __shared__ _Float16 As[2][128][32];   // 16 KB
    __shared__ _Float16 Bs[2][128][32];   // 16 KB
    __shared__ float    red[2][128];      //  1 KB

    const int tid  = threadIdx.x;
    const int lane = tid & 63;
    const int wid  = tid >> 6;            // 0..3
    const int wm   = wid >> 1;            // 0..1
    const int wn   = wid & 1;             // 0..1
    const int l15  = lane & 15;
    const int lq   = lane >> 4;           // 0..3

    // XCD-chunk: per XCD 512 consecutive wgs, n innermost -> n-siblings share A panel in L2
    const int wg    = (blockIdx.x & 7) * 512 + (blockIdx.x >> 3);
    const int mblk  = wg >> 2;            // 0..1023
    const int nblk  = wg & 3;             // 0..3
    const int m0    = mblk * 128;
    const int n0    = nblk * 128;
    const int s_idx = mblk >> 1;
    const int bloc  = (mblk & 1) * 128;

    // A staging: thread covers rows r and r+64, 16B chunk c
    const int r = tid >> 2;               // 0..63
    const int c = tid & 3;                // 0..3
    const float* gA0 = enc + (size_t)(m0 + r) * H_DIM;
    const float* gA1 = enc + (size_t)(m0 + 64 + r) * H_DIM;
    const int aoff = (c ^ ((r >> 1) & 3)) * 8;   // ((r+64)>>1)&3 == (r>>1)&3

    // fragment read chunk (R8-proven)
    const int rch = (lq ^ ((l15 >> 1) & 3)) * 8;

    f32x4 a00, a01, a10, a11;
    auto ldA = [&](int slice) {
        if (slice < 15) {
            int kb = slice * 32 + c * 8;
            a00 = *(const f32x4*)(gA0 + kb); a01 = *(const f32x4*)(gA0 + kb + 4);
            a10 = *(const f32x4*)(gA1 + kb); a11 = *(const f32x4*)(gA1 + kb + 4);
        } else {                          // tail: k in [480,512), guard k >= 500
#pragma unroll
            for (int u = 0; u < 4; ++u) {
                int k0 = 480 + c * 8 + u, k1 = k0 + 4;
                a00[u] = (k0 < H_DIM) ? gA0[k0] : 0.0f;
                a01[u] = (k1 < H_DIM) ? gA0[k1] : 0.0f;
                a10[u] = (k0 < H_DIM) ? gA1[k0] : 0.0f;
                a11[u] = (k1 < H_DIM) ? gA1[k1] : 0.0f;
            }
        }
    };
    auto wrA = [&](int buf) {
        half8_t h0, h1;
#pragma unroll
        for (int u = 0; u < 4; ++u) {
            h0[u] = (_Float16)a00[u]; h0[u + 4] = (_Float16)a01[u];
            h1[u] = (_Float16)a10[u]; h1[u + 4] = (_Float16)a11[u];
        }
        *(half8_t*)&As[buf][r][aoff]      = h0;
        *(half8_t*)&As[buf][64 + r][aoff] = h1;
    };
    auto stB = [&](int buf, int ks) {
        const _Float16* pb = W2i + (size_t)(ks * 4 + nblk) * 4096;
        _Float16* dl = (_Float16*)&Bs[buf][0][0];
        const int s0 = wid * 64, s1 = 256 + wid * 64;
        gld_lds16(pb + (size_t)(s0 + lane) * 8, dl + s0 * 8);
        gld_lds16(pb + (size_t)(s1 + lane) * 8, dl + s1 * 8);
    };

    f32x4 acc[4][4];
#pragma unroll
    for (int a = 0; a < 4; ++a)
#pragma unroll
        for (int b = 0; b < 4; ++b) acc[a][b] = 0;

    // prologue
    stB(0, 0);
    ldA(0);
    wrA(0);

    for (int ks = 0; ks < 16; ++ks) {
        const int cur = ks & 1;
        __syncthreads();
        if (ks < 15) {
            stB(cur ^ 1, ks + 1);
            ldA(ks + 1);
        }
        half8_t af[4], bf[4];
#pragma unroll
        for (int mf = 0; mf < 4; ++mf)
            af[mf] = *(const half8_t*)&As[cur][wm * 64 + mf * 16 + l15][rch];
#pragma unroll
        for (int nf = 0; nf < 4; ++nf)
            bf[nf] = *(const half8_t*)&Bs[cur][wn * 64 + nf * 16 + l15][rch];
#pragma unroll
        for (int mf = 0; mf < 4; ++mf)
#pragma unroll
            for (int nf = 0; nf < 4; ++nf)
                acc[mf][nf] = __builtin_amdgcn_mfma_f32_16x16x32_f16(af[mf], bf[nf], acc[mf][nf], 0, 0, 0);
        if (ks < 15) wrA(cur ^ 1);
    }

    // ---- epilogue: partial scores = sum_h v[h] * tanh(At + E), this N-quarter ----
    float vpv[4];
#pragma unroll
    for (int nf = 0; nf < 4; ++nf) vpv[nf] = vp[n0 + wn * 64 + nf * 16 + l15];

    float pj[4][4];
#pragma unroll
    for (int mf = 0; mf < 4; ++mf)
#pragma unroll
        for (int j = 0; j < 4; ++j) pj[mf][j] = 0.0f;

#pragma unroll
    for (int mf = 0; mf < 4; ++mf) {
#pragma unroll
        for (int nf = 0; nf < 4; ++nf) {
            int h = n0 + wn * 64 + nf * 16 + l15;
            f32x4 av = *(const f32x4*)(At + h * B_DIM + bloc + wm * 64 + mf * 16 + lq * 4);
#pragma unroll
            for (int j = 0; j < 4; ++j) {
                float x  = acc[mf][nf][j] + av[j];
                float xc = fminf(fmaxf(x, -9.0f), 9.0f);
                float e  = __expf(2.0f * xc);
                float th = (e - 1.0f) / (e + 1.0f);
                pj[mf][j] += vpv[nf] * th;
            }
        }
    }

#pragma unroll
    for (int mf = 0; mf < 4; ++mf)
#pragma unroll
        for (int j = 0; j < 4; ++j) {
            float s = pj[mf][j];
            s += __shfl_xor(s, 1); s += __shfl_xor(s, 2);
            s += __shfl_xor(s, 4); s += __shfl_xor(s, 8);
            if (l15 == 0) red[wn][wm * 64 + mf * 16 + lq * 4 + j] = s;
        }
    __syncthreads();
    if (tid < 128) {
        float p = red[0][tid] + red[1][tid];
        sct[(size_t)nblk * M_DIM + (size_t)(bloc + tid) * S_DIM + s_idx] = p;
    }
}

// ---- softmax over S per b, summing the 4 N-partials; out[b][0][s] ----
__global__ void softmax_rows(const float* __restrict__ sct, float* __restrict__ out) {
    int b = blockIdx.x;
    int t = threadIdx.x;                  // 512 threads, one s each
    int lane = t & 63, w = t >> 6;
    size_t idx = (size_t)b * S_DIM + t;
    float v = sct[idx] + sct[idx + M_DIM] + sct[idx + 2 * M_DIM] + sct[idx + 3 * M_DIM];
    float m = v;
#pragma unroll
    for (int off = 1; off < 64; off <<= 1) m = fmaxf(m, __shfl_xor(m, off));
    __shared__ float sm[8], ss[8];
    if (lane == 0) sm[w] = m;
    __syncthreads();
    m = sm[0];
#pragma unroll
    for (int i = 1; i < 8; ++i) m = fmaxf(m, sm[i]);
    float e = __expf(v - m);
    float s = e;
#pragma unroll
    for (int off = 1; off < 64; off <<= 1) s += __shfl_xor(s, off);
    if (lane == 0) ss[w] = s;
    __syncthreads();
    s = ss[0];
#pragma unroll
    for (int i = 1; i < 8; ++i) s += ss[i];
    out[(size_t)b * S_DIM + t] = e / s;
}

extern "C" void kernel_launch(void* const* d_in, const int* in_sizes, int n_in,
                              void* d_out, int out_size, void* d_ws, size_t ws_size,
                              hipStream_t stream) {
    const float* hidden = (const float*)d_in[0];
    const float* enc    = (const float*)d_in[1];
    const float* W      = (const float*)d_in[2];
    const float* b_attn = (const float*)d_in[3];
    const float* v      = (const float*)d_in[4];
    float* out = (float*)d_out;

    char* ws = (char*)d_ws;
    _Float16* W2i = (_Float16*)(ws + WS_W2I);
    float*    At  = (float*)(ws + WS_AT);
    float*    vp  = (float*)(ws + WS_VP);
    float*    sct = (float*)(ws + WS_SC);

    prep_w2_v<<<512, 256, 0, stream>>>(W, v, W2i, vp);
    prep_A<<<256, 512, 0, stream>>>(hidden, W, b_attn, At);
    fused_attn_gemm<<<4096, 256, 0, stream>>>(enc, W2i, At, vp, sct);
    softmax_rows<<<256, 512, 0, stream>>>(sct, out);
}